// Round 9
// baseline (106.073 us; speedup 1.0000x reference)
//
#include <hip/hip_runtime.h>
#include <hip/hip_bf16.h>
#include <math.h>

// Problem: VOCAB=50257, E=64, D=16, DK=32, B*S=65536, membership p=0.05
#define EDIM 64
#define DDOM 16
#define DKDIM 32
#define NTHREADS 256
#define NBA 1024            // job-A blocks in prep (out = h streaming)
#define MBD 48              // blocks per domain in mlp6 (3 blocks/CU)
#define CNT_STRIDE 32       // ints between cnt[d] atomic targets (128 B)

// ws layout: int cnt[16*32] @0 (2048 B) | float w1t[16][32][64] @2048 |
//            float w2t[16][64][32] (x0.1) @133120 | u32 lists[16][ntok] @264192
// lists entries packed: (tokid<<16)|pos  (both < 2^16).
//
// Domain-major + MFMA (R8 structure). R9 deltas:
//  - prep jobC transposes weights into ws so mlp frag loads are float4
//    (w1t[d][ko][e], w2t[d][e][k] pre-scaled by 0.1): 16 b128 loads/lane
//    instead of 64 scattered dwords.
//  - lists pack tokid+pos: gather chain lists->tab (2 hops, was 3).
//  - MBD 32->48: 3 blocks/CU, 12 waves/CU for latency hiding.
// Layouts (16x16x32 bf16, HW-verified): A[m=lane&15][k=quad*8+j];
// C/D col=lane&15,row=quad*4+reg; B[k=quad*8+j][n=lane&15].

typedef __attribute__((ext_vector_type(8))) short bf16x8;
typedef __attribute__((ext_vector_type(4))) float f32x4;

__device__ __forceinline__ short f2bf(float f) {   // fp32 -> bf16 bits, RNE
    unsigned u = __float_as_uint(f);
    u += 0x7FFFu + ((u >> 16) & 1u);
    return (short)(u >> 16);
}

// ---------------------------------------------------------------------------
__global__ void prep_kernel(const int* __restrict__ x,
                            const float* __restrict__ tab,
                            const float* __restrict__ W1,   // [D][E][DK]
                            const float* __restrict__ W2,   // [D][DK][E]
                            const unsigned char* __restrict__ memb,
                            float* __restrict__ out,
                            int* __restrict__ cnt,          // [16*CNT_STRIDE]
                            float* __restrict__ w1t,        // [16][32][64]
                            float* __restrict__ w2t,        // [16][64][32]
                            unsigned int* __restrict__ lists,
                            int ntok, int nbb)
{
    const int thr = threadIdx.x;
    const int bid = blockIdx.x;
    if (bid < NBA) {
        // ---- job A: out = embed_table[x]  (coalesced float4 gather-stream)
        const int nf4 = ntok * 16;
        for (int i = bid * NTHREADS + thr; i < nf4; i += NBA * NTHREADS) {
            int t = i >> 4, s = i & 15;
            int tok = x[t];
            float4 hv = ((const float4*)(tab + (size_t)tok * EDIM))[s];
            ((float4*)(out + (size_t)t * EDIM))[s] = hv;
        }
        return;
    }
    if (bid >= NBA + nbb) {
        // ---- job C: weight transposes (one block per domain)
        const int d = bid - NBA - nbb;
        const float* __restrict__ s1 = W1 + d * (EDIM * DKDIM);   // [e][k]
        float* __restrict__ d1 = w1t + d * (DKDIM * EDIM);        // [k][e]
        for (int i = thr; i < EDIM * DKDIM; i += NTHREADS) {
            int e = i >> 5, k = i & 31;
            d1[k * EDIM + e] = s1[i];
        }
        const float* __restrict__ s2 = W2 + d * (DKDIM * EDIM);   // [k][e]
        float* __restrict__ d2 = w2t + d * (DKDIM * EDIM);        // [e][k]
        for (int i = thr; i < DKDIM * EDIM; i += NTHREADS) {
            int k = i >> 6, e = i & 63;
            d2[e * DKDIM + k] = 0.1f * s2[i];                     // fold 0.1 here
        }
        return;
    }
    // ---- job B: membership dtype detect + per-domain compaction
    __shared__ int det;
    __shared__ int lcnt[DDOM], lbase[DDOM], lpos[DDOM];
    if (thr == 0) det = 0;
    if (thr < DDOM) lcnt[thr] = 0;
    __syncthreads();
    {   // scan first 4096 bytes (membership >= 804112 elements >= 1 B: in-bounds)
        const uint4 v = ((const uint4*)memb)[thr];
        unsigned int w[4] = {v.x, v.y, v.z, v.w};
        int saw = 0;
        #pragma unroll
        for (int dw = 0; dw < 4; ++dw)
            #pragma unroll
            for (int b = 0; b < 4; ++b) {
                unsigned int byte = (w[dw] >> (8 * b)) & 0xFFu;
                if (byte > 1u) saw |= 1;            // bf16 signature bytes
                if (byte == 1u && b != 0) saw |= 2; // '1' at offset %4 != 0 -> u8
            }
        if (saw) atomicOr(&det, saw);
    }
    __syncthreads();
    const int mcode = det;

    const int t = (bid - NBA) * NTHREADS + thr;
    unsigned int m = 0;
    int tok = 0;
    if (t < ntok) {
        tok = x[t];
        if (mcode & 1) {          // bf16 0.0/1.0
            const unsigned short* p = (const unsigned short*)memb + (size_t)tok * DDOM;
            #pragma unroll
            for (int d = 0; d < DDOM; ++d) m |= (unsigned)(p[d] != 0) << d;
        } else if (mcode & 2) {   // uint8
            const unsigned char* p = memb + (size_t)tok * DDOM;
            #pragma unroll
            for (int d = 0; d < DDOM; ++d) m |= (unsigned)(p[d] != 0) << d;
        } else {                  // int32
            const int* p = (const int*)memb + (size_t)tok * DDOM;
            #pragma unroll
            for (int d = 0; d < DDOM; ++d) m |= (unsigned)(p[d] != 0) << d;
        }
    }
    #pragma unroll
    for (int d = 0; d < DDOM; ++d)
        if ((m >> d) & 1u) atomicAdd(&lcnt[d], 1);
    __syncthreads();
    if (thr < DDOM) {
        lbase[thr] = atomicAdd(&cnt[thr * CNT_STRIDE], lcnt[thr]);  // padded target
        lpos[thr] = 0;
    }
    __syncthreads();
    const unsigned int packed = ((unsigned)tok << 16) | (unsigned)(t & 0xFFFF);
    #pragma unroll
    for (int d = 0; d < DDOM; ++d)
        if ((m >> d) & 1u) {
            int p = atomicAdd(&lpos[d], 1);
            lists[(size_t)d * ntok + lbase[d] + p] = packed;
        }
}

// ---------------------------------------------------------------------------
// mlp6: grid = 16 domains x 48 blocks, 256 threads (4 waves), 3 blocks/CU.
// Wave processes 16-token groups; weights live in bf16 MFMA fragments
// loaded once per wave via float4 from the transposed ws copies.
// ---------------------------------------------------------------------------
__global__ __launch_bounds__(256, 3) void mlp6_kernel(
    const unsigned int* __restrict__ lists,
    const int* __restrict__ cnt,
    const float* __restrict__ tab,
    const float* __restrict__ w1t,  // [D][32 ko][64 e]
    const float* __restrict__ w2t,  // [D][64 e][32 k]  (x0.1)
    float* __restrict__ out,
    int ntok)
{
    __shared__ float u_lds[4][16][36];   // per-wave U repack, padded  9.2 KB

    const int thr = threadIdx.x, lane = thr & 63, wid = thr >> 6;
    const int d    = blockIdx.x / MBD;
    const int blk  = blockIdx.x - d * MBD;
    const int n    = cnt[d * CNT_STRIDE];
    if (n == 0) return;

    const int col  = lane & 15;   // n-index inside a 16-wide tile
    const int quad = lane >> 4;   // k-index base = quad*8

    // ---- weight fragments, once per wave (float4 loads, transposed src) ----
    const float* __restrict__ w1d = w1t + d * (DKDIM * EDIM);
    const float* __restrict__ w2d = w2t + d * (DKDIM * EDIM);
    bf16x8 w1f[2][2];   // [K-tile tk][n-half tn]: B[k=e][n=ko]
    #pragma unroll
    for (int tk = 0; tk < 2; ++tk)
        #pragma unroll
        for (int tn = 0; tn < 2; ++tn) {
            const float* p = w1d + (tn * 16 + col) * EDIM + tk * 32 + quad * 8;
            f32x4 a = *(const f32x4*)(p);
            f32x4 b = *(const f32x4*)(p + 4);
            w1f[tk][tn][0] = f2bf(a.x); w1f[tk][tn][1] = f2bf(a.y);
            w1f[tk][tn][2] = f2bf(a.z); w1f[tk][tn][3] = f2bf(a.w);
            w1f[tk][tn][4] = f2bf(b.x); w1f[tk][tn][5] = f2bf(b.y);
            w1f[tk][tn][6] = f2bf(b.z); w1f[tk][tn][7] = f2bf(b.w);
        }
    bf16x8 w2f[4];      // [e-tile te]: B[k][n=e], pre-scaled by 0.1
    #pragma unroll
    for (int te = 0; te < 4; ++te) {
        const float* p = w2d + (te * 16 + col) * DKDIM + quad * 8;
        f32x4 a = *(const f32x4*)(p);
        f32x4 b = *(const f32x4*)(p + 4);
        w2f[te][0] = f2bf(a.x); w2f[te][1] = f2bf(a.y);
        w2f[te][2] = f2bf(a.z); w2f[te][3] = f2bf(a.w);
        w2f[te][4] = f2bf(b.x); w2f[te][5] = f2bf(b.y);
        w2f[te][6] = f2bf(b.z); w2f[te][7] = f2bf(b.w);
    }

    const int ngrp = (n + 15) >> 4;
    for (int g = blk * 4 + wid; g < ngrp; g += MBD * 4) {
        const int base = g * 16;
        const int ti = base + col;                   // lane carries token row m=col
        const bool v = ti < n;
        const unsigned int lst = v ? lists[(size_t)d * ntok + ti] : 0u;
        const int pos   = (int)(lst & 0xFFFFu);
        const int tokid = (int)(lst >> 16);

        // A-fragments of h: A[m=col][k=e=tk*32+quad*8+j]
        const float* __restrict__ hrow = tab + (size_t)tokid * EDIM;
        bf16x8 ha[2];
        #pragma unroll
        for (int tk = 0; tk < 2; ++tk) {
            f32x4 a = *(const f32x4*)(hrow + tk * 32 + quad * 8);
            f32x4 b = *(const f32x4*)(hrow + tk * 32 + quad * 8 + 4);
            ha[tk][0] = f2bf(a.x); ha[tk][1] = f2bf(a.y);
            ha[tk][2] = f2bf(a.z); ha[tk][3] = f2bf(a.w);
            ha[tk][4] = f2bf(b.x); ha[tk][5] = f2bf(b.y);
            ha[tk][6] = f2bf(b.z); ha[tk][7] = f2bf(b.w);
        }

        // ---- step1: U[16 tok x 32 ko] ----
        #pragma unroll
        for (int tn = 0; tn < 2; ++tn) {
            f32x4 acc = {0.f, 0.f, 0.f, 0.f};
            acc = __builtin_amdgcn_mfma_f32_16x16x32_bf16(ha[0], w1f[0][tn], acc, 0, 0, 0);
            acc = __builtin_amdgcn_mfma_f32_16x16x32_bf16(ha[1], w1f[1][tn], acc, 0, 0, 0);
            // gelu on D-frag (D[m=quad*4+r][ko=tn*16+col]) -> u_lds[m][ko]
            #pragma unroll
            for (int r = 0; r < 4; ++r) {
                float u = acc[r];
                float gg, au = fabsf(u);
                if (__builtin_expect(au > 0.35f, 0)) {
                    gg = 0.5f * u * (1.f + erff(u * 0.70710678118654752f));
                } else {
                    float uu = u * u;
                    gg = u * (0.5f + u * (0.3989422804f + uu * (-0.06649038f + uu * 0.00997356f)));
                }
                u_lds[wid][quad * 4 + r][tn * 16 + col] = gg;
            }
        }

        // ---- repack U: D-layout -> A-layout (same-wave RAW, in-order DS) ----
        bf16x8 ua;
        {
            const float* __restrict__ up = &u_lds[wid][col][quad * 8];
            f32x4 a = *(const f32x4*)(up);
            f32x4 b = *(const f32x4*)(up + 4);
            ua[0] = f2bf(a.x); ua[1] = f2bf(a.y); ua[2] = f2bf(a.z); ua[3] = f2bf(a.w);
            ua[4] = f2bf(b.x); ua[5] = f2bf(b.y); ua[6] = f2bf(b.z); ua[7] = f2bf(b.w);
        }

        // ---- step2: C = U x (0.1*W2); atomicAdd into out ----
        #pragma unroll
        for (int te = 0; te < 4; ++te) {
            f32x4 acc = {0.f, 0.f, 0.f, 0.f};
            acc = __builtin_amdgcn_mfma_f32_16x16x32_bf16(ua, w2f[te], acc, 0, 0, 0);
            #pragma unroll
            for (int r = 0; r < 4; ++r) {
                int m  = quad * 4 + r;
                int pm = __shfl(pos, m, 64);      // pos of token row m
                if (base + m < n) {
                    atomicAdd(&out[(size_t)pm * EDIM + te * 16 + col], acc[r]);
                }
            }
        }
    }
}

// ---------------------------------------------------------------------------
// Fallback (ws too small or ntok > 65536): round-2 fused kernel, known-correct.
// ---------------------------------------------------------------------------
__global__ __launch_bounds__(256, 4) void domain_embed_fused(
    const int* __restrict__ x, const float* __restrict__ tab,
    const float* __restrict__ W1, const float* __restrict__ W2,
    const unsigned char* __restrict__ memb, float* __restrict__ out, int ntok)
{
    __shared__ float h_lds[32][EDIM];
    __shared__ float corr[32][EDIM];
    __shared__ int   tok_lds[32];
    __shared__ unsigned int mask_lds[32];
    __shared__ unsigned short pairs[32 * DDOM];
    __shared__ int npairs;
    __shared__ int det_wave[4];
    const int thr = threadIdx.x, lane = thr & 63, wid = thr >> 6;
    const int tok0 = blockIdx.x * 32;
    if (thr < 32) { int t = tok0 + thr; tok_lds[thr] = (t < ntok) ? x[t] : 0; }
    #pragma unroll
    for (int i = 0; i < 8; ++i) ((float*)corr)[thr + i * 256] = 0.f;
    if (thr == 0) npairs = 0;
    {
        const uint4 v = ((const uint4*)memb)[thr];
        unsigned int w[4] = {v.x, v.y, v.z, v.w};
        bool sawbf = false, saw8 = false;
        #pragma unroll
        for (int dw = 0; dw < 4; ++dw)
            #pragma unroll
            for (int b = 0; b < 4; ++b) {
                unsigned int byte = (w[dw] >> (8 * b)) & 0xFFu;
                if (byte > 1u) sawbf = true;
                if (byte == 1u && b != 0) saw8 = true;
            }
        unsigned long long b1 = __ballot(sawbf), b2 = __ballot(saw8);
        if (lane == 0) det_wave[wid] = (b1 ? 1 : 0) | (b2 ? 2 : 0);
    }
    __syncthreads();
    const int mcode = det_wave[0] | det_wave[1] | det_wave[2] | det_wave[3];
    #pragma unroll
    for (int pass = 0; pass < 2; ++pass) {
        int row = pass * 16 + (thr >> 4);
        const float4 hv = ((const float4*)(tab + (size_t)tok_lds[row] * EDIM))[thr & 15];
        ((float4*)&h_lds[row][0])[thr & 15] = hv;
    }
    if (thr < 32) {
        int tokid = tok_lds[thr];
        unsigned int m = 0;
        if (mcode & 1) { const unsigned short* p = (const unsigned short*)memb + (size_t)tokid * DDOM;
            #pragma unroll
            for (int d = 0; d < DDOM; ++d) m |= (unsigned)(p[d] != 0) << d;
        } else if (mcode & 2) { const unsigned char* p = memb + (size_t)tokid * DDOM;
            #pragma unroll
            for (int d = 0; d < DDOM; ++d) m |= (unsigned)(p[d] != 0) << d;
        } else { const int* p = (const int*)memb + (size_t)tokid * DDOM;
            #pragma unroll
            for (int d = 0; d < DDOM; ++d) m |= (unsigned)(p[d] != 0) << d;
        }
        mask_lds[thr] = m;
    }
    __syncthreads();
    for (int cc = thr; cc < 32 * DDOM; cc += 256) {
        int t = cc >> 4, d = cc & 15;
        if ((mask_lds[t] >> d) & 1u) { int idx = atomicAdd(&npairs, 1); pairs[idx] = (unsigned short)cc; }
    }
    __syncthreads();
    const int np = npairs, k = lane & 31, p = lane >> 5;
    for (int pi = wid; pi < np; pi += 4) {
        int cc = pairs[pi], t = cc >> 4, d = cc & 15;
        const float* __restrict__ w1 = W1 + d * (EDIM * DKDIM);
        float u = 0.f;
        #pragma unroll
        for (int j4 = 0; j4 < 8; ++j4) {
            float4 hv = ((const float4*)&h_lds[t][p * 32])[j4];
            int e = p * 32 + j4 * 4;
            u = fmaf(hv.x, w1[(e + 0) * DKDIM + k], u);
            u = fmaf(hv.y, w1[(e + 1) * DKDIM + k], u);
            u = fmaf(hv.z, w1[(e + 2) * DKDIM + k], u);
            u = fmaf(hv.w, w1[(e + 3) * DKDIM + k], u);
        }
        u += __shfl_xor(u, 32, 64);
        float gg, au = fabsf(u);
        if (__builtin_expect(__ballot(au > 0.35f) != 0ull, 0))
            gg = 0.5f * u * (1.f + erff(u * 0.70710678118654752f));
        else { float uu = u * u; gg = u * (0.5f + u * (0.3989422804f + uu * (-0.06649038f + uu * 0.00997356f))); }
        const float* __restrict__ w2 = W2 + d * (DKDIM * EDIM);
        float cp = 0.f;
        #pragma unroll
        for (int kk = 0; kk < DKDIM; ++kk) cp = fmaf(__shfl(gg, kk, 64), w2[kk * EDIM + lane], cp);
        atomicAdd(&corr[t][lane], cp);
    }
    __syncthreads();
    #pragma unroll
    for (int pass = 0; pass < 2; ++pass) {
        int row = pass * 16 + (thr >> 4), gt = tok0 + row;
        if (gt < ntok) {
            float4 hv = ((const float4*)&h_lds[row][0])[thr & 15];
            float4 cv = ((const float4*)&corr[row][0])[thr & 15];
            float4 o = {hv.x + 0.1f * cv.x, hv.y + 0.1f * cv.y, hv.z + 0.1f * cv.z, hv.w + 0.1f * cv.w};
            ((float4*)(out + (size_t)gt * EDIM))[thr & 15] = o;
        }
    }
}

extern "C" void kernel_launch(void* const* d_in, const int* in_sizes, int n_in,
                              void* d_out, int out_size, void* d_ws, size_t ws_size,
                              hipStream_t stream) {
    const int*   x    = (const int*)  d_in[0];
    const float* tab  = (const float*)d_in[1];
    const float* W1   = (const float*)d_in[2];
    const float* W2   = (const float*)d_in[3];
    const unsigned char* memb = (const unsigned char*)d_in[4];
    float* out = (float*)d_out;
    const int ntok = in_sizes[0];

    const size_t cnt_bytes = (size_t)DDOM * CNT_STRIDE * sizeof(int);     // 2048
    const size_t w1t_off   = cnt_bytes;
    const size_t w2t_off   = w1t_off + (size_t)DDOM * DKDIM * EDIM * sizeof(float);
    const size_t lists_off = w2t_off + (size_t)DDOM * DKDIM * EDIM * sizeof(float);
    const size_t need      = lists_off + (size_t)DDOM * (size_t)ntok * sizeof(int);
    if (ws_size >= need && ntok <= 65536) {
        int*   cnt   = (int*)d_ws;
        float* w1t   = (float*)((char*)d_ws + w1t_off);
        float* w2t   = (float*)((char*)d_ws + w2t_off);
        unsigned int* lists = (unsigned int*)((char*)d_ws + lists_off);
        hipMemsetAsync(d_ws, 0, cnt_bytes, stream);        // zero cnt (ws poisoned)
        const int nbb = (ntok + NTHREADS - 1) / NTHREADS;
        prep_kernel<<<NBA + nbb + DDOM, NTHREADS, 0, stream>>>(
            x, tab, W1, W2, memb, out, cnt, w1t, w2t, lists, ntok, nbb);
        mlp6_kernel<<<DDOM * MBD, NTHREADS, 0, stream>>>(
            lists, cnt, tab, w1t, w2t, out, ntok);
    } else {
        const int blocks = (ntok + 31) / 32;
        domain_embed_fused<<<blocks, NTHREADS, 0, stream>>>(x, tab, W1, W2, memb, out, ntok);
    }
}